// Round 5
// baseline (339.731 us; speedup 1.0000x reference)
//
#include <hip/hip_runtime.h>

#define D_FEAT 64
#define CHUNK 8192
#define BSHIFT 9
#define BSIZE 512

typedef unsigned int uint;
typedef unsigned short ushort;

static __device__ __forceinline__ ushort f2bf(float f) {
    uint u = __float_as_uint(f);
    uint r = (u + 0x7fffu + ((u >> 16) & 1u)) >> 16;   // RNE
    return (ushort)r;
}
static __device__ __forceinline__ float bf2f(ushort b) {
    return __uint_as_float(((uint)b) << 16);
}

// ---------- Phase A: bucket histogram (bucket = dst >> 9) ----------
__global__ void bucket_hist(const int* __restrict__ dst, int* __restrict__ bcount, int n_edges) {
    __shared__ int h[256];
    h[threadIdx.x] = 0;
    __syncthreads();
    for (int e = blockIdx.x * blockDim.x + threadIdx.x; e < n_edges; e += gridDim.x * blockDim.x)
        atomicAdd(&h[dst[e] >> BSHIFT], 1);
    __syncthreads();
    int v = h[threadIdx.x];
    if (v) atomicAdd(&bcount[threadIdx.x], v);
}

// ---------- Phase B: scan 256 bucket counts -> bbase, bcursor ----------
__global__ void bucket_scan(const int* __restrict__ bcount, int* __restrict__ bbase,
                            int* __restrict__ bcursor) {
    __shared__ int s[256];
    int t = threadIdx.x;
    int v = bcount[t];
    s[t] = v;
    __syncthreads();
    for (int off = 1; off < 256; off <<= 1) {
        int u = (t >= off) ? s[t - off] : 0;
        __syncthreads();
        s[t] += u;
        __syncthreads();
    }
    int excl = s[t] - v;
    bbase[t] = excl;
    bcursor[t] = excl;
}

// ---------- Phase C: per-chunk counting sort by bucket, contiguous flush ----------
__global__ __launch_bounds__(256) void partition_kernel(
        const int* __restrict__ src, const int* __restrict__ dst,
        const float* __restrict__ w, int* __restrict__ bcursor,
        int2* __restrict__ inter, int n_edges) {
    __shared__ int hist[256];
    __shared__ int lofs[256];
    __shared__ int cur[256];
    __shared__ int gbase[256];
    __shared__ int2 buf[CHUNK];          // 64 KB staging
    int t = threadIdx.x;
    int beg = blockIdx.x * CHUNK;
    int end = min(beg + CHUNK, n_edges);

    hist[t] = 0;
    __syncthreads();
    for (int i = beg + t; i < end; i += 256)
        atomicAdd(&hist[dst[i] >> BSHIFT], 1);
    __syncthreads();
    int v = hist[t];
    lofs[t] = v;
    __syncthreads();
    for (int off = 1; off < 256; off <<= 1) {
        int u = (t >= off) ? lofs[t - off] : 0;
        __syncthreads();
        lofs[t] += u;
        __syncthreads();
    }
    int excl = lofs[t] - v;
    __syncthreads();
    lofs[t] = excl;
    cur[t]  = excl;
    __syncthreads();
    for (int i = beg + t; i < end; i += 256) {
        int d = dst[i];
        int b = d >> BSHIFT;
        int p = atomicAdd(&cur[b], 1);
        buf[p] = make_int2((src[i] << BSHIFT) | (d & (BSIZE - 1)), __float_as_int(w[i]));
    }
    __syncthreads();
    if (hist[t]) gbase[t] = atomicAdd(&bcursor[t], hist[t]);
    __syncthreads();
    int wid = t >> 6, lane = t & 63;
    for (int b = wid; b < 256; b += 4) {
        int c = hist[b];
        if (!c) continue;
        int lo = lofs[b], gb = gbase[b];
        for (int k = lane; k < c; k += 64)
            inter[gb + k] = buf[lo + k];
    }
}

// ---------- Phase D: per-bucket counting sort by node; emits row_ptr ----------
__global__ __launch_bounds__(512) void finalize_kernel(
        const int2* __restrict__ inter, const int* __restrict__ bbase,
        const int* __restrict__ bcount, int2* __restrict__ edges,
        int* __restrict__ row_ptr, int n_nodes, int n_edges) {
    __shared__ int hist[BSIZE];
    __shared__ int cur[BSIZE];
    int b = blockIdx.x;
    int t = threadIdx.x;
    int base = bbase[b];
    int cnt  = bcount[b];

    hist[t] = 0;
    __syncthreads();
    for (int i = t; i < cnt; i += BSIZE)
        atomicAdd(&hist[inter[base + i].x & (BSIZE - 1)], 1);
    __syncthreads();
    int v = hist[t];
    cur[t] = v;
    __syncthreads();
    for (int off = 1; off < BSIZE; off <<= 1) {
        int u = (t >= off) ? cur[t - off] : 0;
        __syncthreads();
        cur[t] += u;
        __syncthreads();
    }
    int excl = cur[t] - v;
    int node = (b << BSHIFT) + t;
    if (node < n_nodes) row_ptr[node] = base + excl;
    if (b == 0 && t == 0) row_ptr[n_nodes] = n_edges;
    __syncthreads();
    cur[t] = excl;
    __syncthreads();
    for (int i = t; i < cnt; i += BSIZE) {
        int2 r = inter[base + i];
        int dlo = r.x & (BSIZE - 1);
        int p = atomicAdd(&cur[dlo], 1);
        edges[base + p] = make_int2(r.x >> BSHIFT, r.y);   // (src, w-bits)
    }
}

// ---------- convert: f32 features -> bf16 ----------
__global__ void cvt_bf16(const float* __restrict__ in, ushort* __restrict__ out, int n) {
    int i = blockIdx.x * blockDim.x + threadIdx.x;
    int stride = gridDim.x * blockDim.x;
    for (; i < n; i += stride) out[i] = f2bf(in[i]);
}

// ---------- gather hop v2: wave = node; 4 rows per wave-load ----------
// lane layout: r = lane>>4 (row-group 0..3), c = lane&15 (features 4c..4c+3)
template <bool OUT_BF16>
__global__ __launch_bounds__(256) void gather_hop(
        const ushort* __restrict__ h, const int2* __restrict__ edges,
        const int* __restrict__ row_ptr, void* __restrict__ out_v, int n_nodes) {
    int node = __builtin_amdgcn_readfirstlane(blockIdx.x * 4 + (threadIdx.x >> 6));
    if (node >= n_nodes) return;
    int lane = threadIdx.x & 63;
    int r = lane >> 4;
    int c = lane & 15;
    int beg = __builtin_amdgcn_readfirstlane(row_ptr[node]);
    int end = __builtin_amdgcn_readfirstlane(row_ptr[node + 1]);

    float a0 = 0.f, a1 = 0.f, a2 = 0.f, a3 = 0.f;
    int j = beg;
    // main loop: 32 edges per iteration, 32 rows (4 KB) in flight
    for (; j + 32 <= end; j += 32) {
        #pragma unroll
        for (int s = 0; s < 8; ++s) {
            int e = j + s * 4 + r;                       // always < end
            int2 ev = edges[e];                          // 8B, uniform per 16-lane group
            const ushort4 hv = *(const ushort4*)&h[((size_t)ev.x << 6) + (c << 2)];
            float wv = __int_as_float(ev.y);
            a0 += wv * bf2f(hv.x);
            a1 += wv * bf2f(hv.y);
            a2 += wv * bf2f(hv.z);
            a3 += wv * bf2f(hv.w);
        }
    }
    // tail: 8 edges per step, guarded
    for (; j < end; j += 8) {
        #pragma unroll
        for (int s = 0; s < 2; ++s) {
            int e = j + s * 4 + r;
            if (e < end) {
                int2 ev = edges[e];
                const ushort4 hv = *(const ushort4*)&h[((size_t)ev.x << 6) + (c << 2)];
                float wv = __int_as_float(ev.y);
                a0 += wv * bf2f(hv.x);
                a1 += wv * bf2f(hv.y);
                a2 += wv * bf2f(hv.z);
                a3 += wv * bf2f(hv.w);
            }
        }
    }
    // fold the 4 row-groups (lanes l, l+16, l+32, l+48)
    a0 += __shfl_xor(a0, 16); a0 += __shfl_xor(a0, 32);
    a1 += __shfl_xor(a1, 16); a1 += __shfl_xor(a1, 32);
    a2 += __shfl_xor(a2, 16); a2 += __shfl_xor(a2, 32);
    a3 += __shfl_xor(a3, 16); a3 += __shfl_xor(a3, 32);

    if (lane < 16) {
        if (OUT_BF16) {
            ushort4 o;
            o.x = f2bf(a0); o.y = f2bf(a1); o.z = f2bf(a2); o.w = f2bf(a3);
            ((ushort4*)out_v)[((size_t)node << 4) + c] = o;   // 8B x 16 lanes = 128B row
        } else {
            float4 o;
            o.x = a0; o.y = a1; o.z = a2; o.w = a3;
            ((float4*)out_v)[((size_t)node << 4) + c] = o;    // 16B x 16 lanes = 256B row
        }
    }
}

extern "C" void kernel_launch(void* const* d_in, const int* in_sizes, int n_in,
                              void* d_out, int out_size, void* d_ws, size_t ws_size,
                              hipStream_t stream) {
    const float* x   = (const float*)d_in[0];
    const float* ew  = (const float*)d_in[1];
    const int*   src = (const int*)d_in[2];
    const int*   dst = (const int*)d_in[3];
    float* out = (float*)d_out;

    const int n_nodes = in_sizes[0] / D_FEAT;   // 100000
    const int n_edges = in_sizes[1];            // 3200000
    const int nbuck   = (n_nodes + BSIZE - 1) >> BSHIFT;   // 196
    const int n_feat_total = n_nodes * D_FEAT;

    const size_t ed_bytes = (size_t)n_edges * 8;           // 25.6 MB
    const size_t bf_bytes = (size_t)n_feat_total * 2;      // 12.8 MB

    // workspace layout: [region0: inter(25.6MB) -> later x_bf(12.8)+buf1(12.8)]
    //                   [edges 25.6MB][row_ptr][bcount][bbase][bcursor]
    char* ws = (char*)d_ws;
    int2*   inter  = (int2*)ws;
    ushort* x_bf   = (ushort*)ws;
    ushort* buf1   = (ushort*)(ws + bf_bytes);
    ws += (ed_bytes > 2 * bf_bytes ? ed_bytes : 2 * bf_bytes);
    int2* edges    = (int2*)ws;                 ws += ed_bytes;
    int*  row_ptr  = (int*)ws;                  ws += (size_t)(n_nodes + 1) * 4;
    int*  bcount   = (int*)ws;                  ws += 256 * 4;
    int*  bbase    = (int*)ws;                  ws += 256 * 4;
    int*  bcursor  = (int*)ws;

    // --- build dst-sorted CSR (bucketed counting sort); uses inter ---
    hipMemsetAsync(bcount, 0, 256 * 4, stream);
    bucket_hist<<<512, 256, 0, stream>>>(dst, bcount, n_edges);
    bucket_scan<<<1, 256, 0, stream>>>(bcount, bbase, bcursor);
    partition_kernel<<<(n_edges + CHUNK - 1) / CHUNK, 256, 0, stream>>>(
        src, dst, ew, bcursor, inter, n_edges);
    finalize_kernel<<<nbuck, BSIZE, 0, stream>>>(
        inter, bbase, bcount, edges, row_ptr, n_nodes, n_edges);

    // --- convert x to bf16 (inter region now free) ---
    cvt_bf16<<<1024, 256, 0, stream>>>(x, x_bf, n_feat_total);

    // --- 3 gather hops: x_bf -> buf1 -> x_bf -> out(f32) ---
    const int grd = (n_nodes + 3) / 4;
    gather_hop<true ><<<grd, 256, 0, stream>>>(x_bf, edges, row_ptr, buf1, n_nodes);
    gather_hop<true ><<<grd, 256, 0, stream>>>(buf1, edges, row_ptr, x_bf, n_nodes);
    gather_hop<false><<<grd, 256, 0, stream>>>(x_bf, edges, row_ptr, out,  n_nodes);
}

// Round 6
// 318.228 us; speedup vs baseline: 1.0676x; 1.0676x over previous
//
#include <hip/hip_runtime.h>

#define D_FEAT 64
#define CHUNK 8192
#define BSHIFT 9
#define BSIZE 512

typedef unsigned int uint;
typedef unsigned short ushort;

static __device__ __forceinline__ ushort f2bf(float f) {
    uint u = __float_as_uint(f);
    uint r = (u + 0x7fffu + ((u >> 16) & 1u)) >> 16;   // RNE
    return (ushort)r;
}
static __device__ __forceinline__ float bf2f(ushort b) {
    return __uint_as_float(((uint)b) << 16);
}

// ---------- Phase A: bucket histogram (bucket = dst >> 9) ----------
__global__ void bucket_hist(const int* __restrict__ dst, int* __restrict__ bcount, int n_edges) {
    __shared__ int h[256];
    h[threadIdx.x] = 0;
    __syncthreads();
    for (int e = blockIdx.x * blockDim.x + threadIdx.x; e < n_edges; e += gridDim.x * blockDim.x)
        atomicAdd(&h[dst[e] >> BSHIFT], 1);
    __syncthreads();
    int v = h[threadIdx.x];
    if (v) atomicAdd(&bcount[threadIdx.x], v);
}

// ---------- Phase B: scan 256 bucket counts -> bbase, bcursor ----------
__global__ void bucket_scan(const int* __restrict__ bcount, int* __restrict__ bbase,
                            int* __restrict__ bcursor) {
    __shared__ int s[256];
    int t = threadIdx.x;
    int v = bcount[t];
    s[t] = v;
    __syncthreads();
    for (int off = 1; off < 256; off <<= 1) {
        int u = (t >= off) ? s[t - off] : 0;
        __syncthreads();
        s[t] += u;
        __syncthreads();
    }
    int excl = s[t] - v;
    bbase[t] = excl;
    bcursor[t] = excl;
}

// ---------- Phase C: per-chunk counting sort by bucket, contiguous flush ----------
__global__ __launch_bounds__(256) void partition_kernel(
        const int* __restrict__ src, const int* __restrict__ dst,
        const float* __restrict__ w, int* __restrict__ bcursor,
        int2* __restrict__ inter, int n_edges) {
    __shared__ int hist[256];
    __shared__ int lofs[256];
    __shared__ int cur[256];
    __shared__ int gbase[256];
    __shared__ int2 buf[CHUNK];          // 64 KB staging
    int t = threadIdx.x;
    int beg = blockIdx.x * CHUNK;
    int end = min(beg + CHUNK, n_edges);

    hist[t] = 0;
    __syncthreads();
    for (int i = beg + t; i < end; i += 256)
        atomicAdd(&hist[dst[i] >> BSHIFT], 1);
    __syncthreads();
    int v = hist[t];
    lofs[t] = v;
    __syncthreads();
    for (int off = 1; off < 256; off <<= 1) {
        int u = (t >= off) ? lofs[t - off] : 0;
        __syncthreads();
        lofs[t] += u;
        __syncthreads();
    }
    int excl = lofs[t] - v;
    __syncthreads();
    lofs[t] = excl;
    cur[t]  = excl;
    __syncthreads();
    for (int i = beg + t; i < end; i += 256) {
        int d = dst[i];
        int b = d >> BSHIFT;
        int p = atomicAdd(&cur[b], 1);
        buf[p] = make_int2((src[i] << BSHIFT) | (d & (BSIZE - 1)), __float_as_int(w[i]));
    }
    __syncthreads();
    if (hist[t]) gbase[t] = atomicAdd(&bcursor[t], hist[t]);
    __syncthreads();
    int wid = t >> 6, lane = t & 63;
    for (int b = wid; b < 256; b += 4) {
        int c = hist[b];
        if (!c) continue;
        int lo = lofs[b], gb = gbase[b];
        for (int k = lane; k < c; k += 64)
            inter[gb + k] = buf[lo + k];
    }
}

// ---------- Phase D: per-bucket counting sort by node; emits row_ptr + packed 4B edges ----------
// packed edge: (src << 15) | wq15, w ≈ (wq + 0.5) / 32768
__global__ __launch_bounds__(512) void finalize_kernel(
        const int2* __restrict__ inter, const int* __restrict__ bbase,
        const int* __restrict__ bcount, uint* __restrict__ edges,
        int* __restrict__ row_ptr, int n_nodes, int n_edges) {
    __shared__ int hist[BSIZE];
    __shared__ int cur[BSIZE];
    int b = blockIdx.x;
    int t = threadIdx.x;
    int base = bbase[b];
    int cnt  = bcount[b];

    hist[t] = 0;
    __syncthreads();
    for (int i = t; i < cnt; i += BSIZE)
        atomicAdd(&hist[inter[base + i].x & (BSIZE - 1)], 1);
    __syncthreads();
    int v = hist[t];
    cur[t] = v;
    __syncthreads();
    for (int off = 1; off < BSIZE; off <<= 1) {
        int u = (t >= off) ? cur[t - off] : 0;
        __syncthreads();
        cur[t] += u;
        __syncthreads();
    }
    int excl = cur[t] - v;
    int node = (b << BSHIFT) + t;
    if (node < n_nodes) row_ptr[node] = base + excl;
    if (b == 0 && t == 0) row_ptr[n_nodes] = n_edges;
    __syncthreads();
    cur[t] = excl;
    __syncthreads();
    for (int i = t; i < cnt; i += BSIZE) {
        int2 r = inter[base + i];
        int dlo = r.x & (BSIZE - 1);
        int p = atomicAdd(&cur[dlo], 1);
        float wf = __int_as_float(r.y);
        uint wq = (uint)(wf * 32768.0f);
        if (wq > 32767u) wq = 32767u;
        edges[base + p] = ((uint)(r.x >> BSHIFT) << 15) | wq;
    }
}

// ---------- convert: f32 features -> bf16, vectorized ----------
__global__ void cvt_bf16(const float* __restrict__ in, ushort* __restrict__ out, int n4) {
    int i = blockIdx.x * blockDim.x + threadIdx.x;
    int stride = gridDim.x * blockDim.x;
    for (; i < n4; i += stride) {
        float4 v = ((const float4*)in)[i];
        ushort4 o;
        o.x = f2bf(v.x); o.y = f2bf(v.y); o.z = f2bf(v.z); o.w = f2bf(v.w);
        ((ushort4*)out)[i] = o;
    }
}

// ---------- gather hop: one wave per node; scalar packed-edge stream ----------
template <int DEPTH, bool OUT_BF16>
__global__ __launch_bounds__(256) void gather_hop(
        const ushort* __restrict__ h, const uint* __restrict__ edges,
        const int* __restrict__ row_ptr, void* __restrict__ out_v, int n_nodes) {
    int node = __builtin_amdgcn_readfirstlane(blockIdx.x * 4 + (threadIdx.x >> 6));
    if (node >= n_nodes) return;
    int f = threadIdx.x & 63;
    int beg = __builtin_amdgcn_readfirstlane(row_ptr[node]);
    int end = __builtin_amdgcn_readfirstlane(row_ptr[node + 1]);
    float acc = 0.0f;
    int j = beg;
    for (; j + DEPTH <= end; j += DEPTH) {
        #pragma unroll
        for (int k = 0; k < DEPTH; ++k) {
            uint ev = edges[j + k];                       // uniform addr -> scalar load
            float wv = (float)(ev & 32767u) * (1.0f / 32768.0f) + (1.0f / 65536.0f);
            acc += wv * bf2f(h[((size_t)(ev >> 15) << 6) + f]);
        }
    }
    for (; j < end; ++j) {
        uint ev = edges[j];
        float wv = (float)(ev & 32767u) * (1.0f / 32768.0f) + (1.0f / 65536.0f);
        acc += wv * bf2f(h[((size_t)(ev >> 15) << 6) + f]);
    }
    if (OUT_BF16) ((ushort*)out_v)[((size_t)node << 6) + f] = f2bf(acc);
    else          ((float*)out_v)[((size_t)node << 6) + f]  = acc;
}

extern "C" void kernel_launch(void* const* d_in, const int* in_sizes, int n_in,
                              void* d_out, int out_size, void* d_ws, size_t ws_size,
                              hipStream_t stream) {
    const float* x   = (const float*)d_in[0];
    const float* ew  = (const float*)d_in[1];
    const int*   src = (const int*)d_in[2];
    const int*   dst = (const int*)d_in[3];
    float* out = (float*)d_out;

    const int n_nodes = in_sizes[0] / D_FEAT;   // 100000
    const int n_edges = in_sizes[1];            // 3200000
    const int nbuck   = (n_nodes + BSIZE - 1) >> BSHIFT;   // 196
    const int n_feat_total = n_nodes * D_FEAT;

    const size_t ed8_bytes = (size_t)n_edges * 8;          // 25.6 MB (inter)
    const size_t ed4_bytes = (size_t)n_edges * 4;          // 12.8 MB (packed edges)
    const size_t bf_bytes  = (size_t)n_feat_total * 2;     // 12.8 MB

    // workspace: [region0: inter(25.6MB) -> later x_bf(12.8)+buf1(12.8)]
    //            [edges 12.8MB][row_ptr][bcount][bbase][bcursor]
    char* ws = (char*)d_ws;
    int2*   inter  = (int2*)ws;
    ushort* x_bf   = (ushort*)ws;
    ushort* buf1   = (ushort*)(ws + bf_bytes);
    ws += (ed8_bytes > 2 * bf_bytes ? ed8_bytes : 2 * bf_bytes);
    uint* edges    = (uint*)ws;                 ws += ed4_bytes;
    int*  row_ptr  = (int*)ws;                  ws += (size_t)(n_nodes + 1) * 4;
    int*  bcount   = (int*)ws;                  ws += 256 * 4;
    int*  bbase    = (int*)ws;                  ws += 256 * 4;
    int*  bcursor  = (int*)ws;

    // --- build dst-sorted CSR (bucketed counting sort); uses inter ---
    hipMemsetAsync(bcount, 0, 256 * 4, stream);
    bucket_hist<<<512, 256, 0, stream>>>(dst, bcount, n_edges);
    bucket_scan<<<1, 256, 0, stream>>>(bcount, bbase, bcursor);
    partition_kernel<<<(n_edges + CHUNK - 1) / CHUNK, 256, 0, stream>>>(
        src, dst, ew, bcursor, inter, n_edges);
    finalize_kernel<<<nbuck, BSIZE, 0, stream>>>(
        inter, bbase, bcount, edges, row_ptr, n_nodes, n_edges);

    // --- convert x to bf16 (inter region now free) ---
    cvt_bf16<<<1024, 256, 0, stream>>>(x, x_bf, n_feat_total / 4);

    // --- 3 gather hops: x_bf -> buf1 -> x_bf -> out(f32) ---
    // hop2 runs DEPTH=16 as a within-round A/B vs DEPTH=8 (hops 1,3).
    const int grd = (n_nodes + 3) / 4;
    gather_hop< 8, true ><<<grd, 256, 0, stream>>>(x_bf, edges, row_ptr, buf1, n_nodes);
    gather_hop<16, true ><<<grd, 256, 0, stream>>>(buf1, edges, row_ptr, x_bf, n_nodes);
    gather_hop< 8, false><<<grd, 256, 0, stream>>>(x_bf, edges, row_ptr, out,  n_nodes);
}